// Round 10
// baseline (148.518 us; speedup 1.0000x reference)
//
#include <hip/hip_runtime.h>
#include <math.h>

#define SMK    2048
#define TAPS   32
#define OUTLEN (SMK + TAPS - 1)   // 2079
#define PAD    32
#define SLOTS  (PAD + SMK + PAD)  // 2112 float2 slots
#define NF4    (SLOTS / 2)        // 1056 float4 slots
#define MDFT   64

typedef float v2f __attribute__((ext_vector_type(2)));

// Involution swizzle on float4 slots (r5-measured: conflicts 8.06e7 -> 7.2e6
// for exactly this read shape). Applied to BOTH staging writes and reads.
__device__ __forceinline__ int swz4(int s) { return s ^ ((s >> 3) & 7); }

__device__ __forceinline__ float rfl(float x) {
    return __int_as_float(__builtin_amdgcn_readfirstlane(__float_as_int(x)));
}

// Budget: 16 acc + 32 window + ~10 misc ~= 58 VGPR -> 8 blocks/CU.
__global__ __launch_bounds__(256, 8)
void conv_kernel(const float* __restrict__ input,
                 const float* __restrict__ cof,
                 float* __restrict__ out0,
                 float* __restrict__ out1)
{
    __shared__ float4 S4[NF4];
    __shared__ float2 s_tw[MDFT];

    const int tid = threadIdx.x;
    const int row = blockIdx.x;

    // ---- stage signal row (16 KB) into swz4 LDS ----
    const float4* gin = (const float4*)(input + (size_t)row * (SMK * 2));
    #pragma unroll
    for (int k = 0; k < 4; ++k)
        S4[swz4(16 + tid + 256 * k)] = gin[tid + 256 * k];
    if (tid < 16) {
        S4[swz4(tid)] = make_float4(0.f, 0.f, 0.f, 0.f);          // front pad
    } else if (tid < 32) {
        S4[swz4(1024 + tid)] = make_float4(0.f, 0.f, 0.f, 0.f);   // back pad
    }
    if (tid >= 64 && tid < 128) {                                 // twiddles
        int j = tid - 64;
        float sv, cv;
        __sincosf(-2.0f * (float)M_PI * (float)j / (float)MDFT, &sv, &cv);
        s_tw[j] = make_float2(cv, sv);
    }

    // ---- taps -> SGPR (block-uniform) ----
    const float2* __restrict__ ct = (const float2*)(cof + (size_t)row * (TAPS * 2));
    float hre[TAPS], him[TAPS];
    #pragma unroll
    for (int l = 0; l < TAPS; ++l) {
        float2 tv = ct[l];
        hre[l] = rfl(tv.x);
        him[l] = rfl(tv.y);
    }
    __syncthreads();

    float2* go2 = (float2*)(out0 + (size_t)row * (OUTLEN * 2));

    // ---- main: 8 consecutive outputs t = 8*tid+1 .. 8*tid+8 ----
    const int t0 = 8 * tid + 1;

    v2f acc[8];
    #pragma unroll
    for (int k = 0; k < 8; ++k) acc[k] = (v2f)(0.f);

    #pragma unroll
    for (int c = 0; c < 4; ++c) {
        // chunk c: taps l = 8c..8c+7. Window float2 slots
        // [PAD+t0-8c-7, PAD+t0-8c+8] -> 8 float4 from base4 = 4*tid+13-4c.
        const int base4 = 4 * tid + 13 - 4 * c;
        float4 w4[8];
        #pragma unroll
        for (int i = 0; i < 8; ++i) w4[i] = S4[swz4(base4 + i)];

        #pragma unroll
        for (int lp = 0; lp < 8; ++lp) {
            const int l = 8 * c + lp;
            const v2f hva = {  hre[l], him[l] };   // (hr, hi)
            const v2f hvb = { -him[l], hre[l] };   // (-hi, hr)
            #pragma unroll
            for (int k = 0; k < 8; ++k) {
                const int m = k - lp + 7;          // 0..14, compile-time
                const float sx = (m & 1) ? w4[m >> 1].z : w4[m >> 1].x;
                const float sy = (m & 1) ? w4[m >> 1].w : w4[m >> 1].y;
                acc[k] = __builtin_elementwise_fma((v2f){ sx, sx }, hva, acc[k]);
                acc[k] = __builtin_elementwise_fma((v2f){ sy, sy }, hvb, acc[k]);
            }
        }
        // contain per-chunk window live-range (don't hoist next chunk's reads)
        __builtin_amdgcn_sched_barrier(0);
    }

    #pragma unroll
    for (int k = 0; k < 8; ++k)
        go2[t0 + k] = make_float2(acc[k].x, acc[k].y);

    // ---- wave 0 extra: fused 64-pt DFT of zero-padded taps ----
    if (tid < MDFT) {
        const int kk = tid;
        v2f aA = (v2f)(0.f), aB = (v2f)(0.f);
        #pragma unroll
        for (int l = 0; l < TAPS; ++l) {
            const v2f hv = { hre[l], him[l] };
            float2 w = s_tw[(kk * l) & (MDFT - 1)];
            aA = __builtin_elementwise_fma((v2f){ w.x, w.x }, hv, aA);
            aB = __builtin_elementwise_fma((v2f){ w.y, w.y }, hv, aB);
        }
        ((float2*)out1)[(size_t)row * MDFT + kk] =
            make_float2(aA.x - aB.y, aA.y + aB.x);
    }
    // ---- wave 2 extra: leftover outputs t=0 and t=2049..2078 ----
    else if (tid >= 128 && tid <= 158) {
        const int t = (tid == 158) ? 0 : (2049 + (tid - 128));
        v2f aA = (v2f)(0.f), aB = (v2f)(0.f);
        #pragma unroll
        for (int l = 0; l < TAPS; ++l) {
            const v2f hv = { hre[l], him[l] };
            const int p = PAD + t - l;             // pads supply zeros
            float4 v = S4[swz4(p >> 1)];
            const float sx = (p & 1) ? v.z : v.x;
            const float sy = (p & 1) ? v.w : v.y;
            aA = __builtin_elementwise_fma((v2f){ sx, sx }, hv, aA);
            aB = __builtin_elementwise_fma((v2f){ sy, sy }, hv, aB);
        }
        go2[t] = make_float2(aA.x - aB.y, aA.y + aB.x);
    }
}

extern "C" void kernel_launch(void* const* d_in, const int* in_sizes, int n_in,
                              void* d_out, int out_size, void* d_ws, size_t ws_size,
                              hipStream_t stream)
{
    const float* input = (const float*)d_in[0];  // (N,P,2048,2) fp32
    const float* cof   = (const float*)d_in[1];  // (N,P,32,2)   fp32
    // d_in[2] is M (=64), compile-time here.

    const int NP = in_sizes[0] / (SMK * 2);      // 16384

    float* out0 = (float*)d_out;                           // (NP, 2079, 2)
    float* out1 = out0 + (size_t)NP * OUTLEN * 2;          // (NP, 64, 2)

    conv_kernel<<<NP, 256, 0, stream>>>(input, cof, out0, out1);
}

// Round 11
// 135.581 us; speedup vs baseline: 1.0954x; 1.0954x over previous
//
#include <hip/hip_runtime.h>
#include <math.h>

#define SMK    2048
#define TAPS   32
#define OUTLEN (SMK + TAPS - 1)   // 2079
#define PAD    32
#define SLOTS  (PAD + SMK + PAD)  // 2112 float2 slots
#define NF4    (SLOTS / 2)        // 1056 float4 slots, LINEAR
#define MDFT   64

typedef float v2f __attribute__((ext_vector_type(2)));

__device__ __forceinline__ float rfl(float x) {
    return __int_as_float(__builtin_amdgcn_readfirstlane(__float_as_int(x)));
}

// W=2 consecutive outputs x 4 strided groups:
//  - window reads: 5 ds_read_b128 per 8-tap chunk at 16B lane stride
//    (lane-contiguous, conflict-free, LINEAR lds — no swizzle anywhere)
//  - stores: 16B/lane stride -> 128 line-requests/wave (r10 had 512)
//  - live set ~50 VGPR -> 8 blocks/CU pinned.
__global__ __launch_bounds__(256, 8)
void conv_kernel(const float* __restrict__ input,
                 const float* __restrict__ cof,
                 float* __restrict__ out0,
                 float* __restrict__ out1)
{
    __shared__ float4 S4[NF4];
    __shared__ float2 s_tw[MDFT];

    const int tid = threadIdx.x;
    const int row = blockIdx.x;

    // ---- stage signal row (16 KB) into linear LDS ----
    const float4* gin = (const float4*)(input + (size_t)row * (SMK * 2));
    #pragma unroll
    for (int k = 0; k < 4; ++k) S4[16 + tid + 256 * k] = gin[tid + 256 * k];
    if (tid < 16) {
        S4[tid] = make_float4(0.f, 0.f, 0.f, 0.f);            // front pad
    } else if (tid < 32) {
        S4[1024 + tid] = make_float4(0.f, 0.f, 0.f, 0.f);     // back pad
    }
    if (tid >= 64 && tid < 128) {                             // twiddles
        int j = tid - 64;
        float sv, cv;
        __sincosf(-2.0f * (float)M_PI * (float)j / (float)MDFT, &sv, &cv);
        s_tw[j] = make_float2(cv, sv);
    }

    // ---- taps -> SGPR (block-uniform) ----
    const float2* __restrict__ ct = (const float2*)(cof + (size_t)row * (TAPS * 2));
    float hre[TAPS], him[TAPS];
    #pragma unroll
    for (int l = 0; l < TAPS; ++l) {
        float2 tv = ct[l];
        hre[l] = rfl(tv.x);
        him[l] = rfl(tv.y);
    }
    __syncthreads();

    float2* go2 = (float2*)(out0 + (size_t)row * (OUTLEN * 2));

    // ---- main: outputs t = 2*tid+1+512*j + k, k<2 (covers t in [1,2048]) ----
    #pragma unroll 1
    for (int j = 0; j < 4; ++j) {
        const int t0 = 2 * tid + 1 + 512 * j;

        v2f accA[2], accB[2];
        #pragma unroll
        for (int k = 0; k < 2; ++k) { accA[k] = (v2f)(0.f); accB[k] = (v2f)(0.f); }

        #pragma unroll
        for (int c = 0; c < 4; ++c) {
            // chunk c: taps l=8c..8c+7; window f2 slots
            // [PAD+t0-8c-7, PAD+t0-8c+1] (9 slots, even start) -> 5 float4
            const int base4 = tid + 13 + 256 * j - 4 * c;
            float4 w4[5];
            #pragma unroll
            for (int i = 0; i < 5; ++i) w4[i] = S4[base4 + i];

            #pragma unroll
            for (int lp = 0; lp < 8; ++lp) {
                const int l = 8 * c + lp;
                const v2f hv = { hre[l], him[l] };     // SGPR pair, uniform
                #pragma unroll
                for (int k = 0; k < 2; ++k) {
                    const int m = k - lp + 7;          // 0..8, compile-time
                    const float sx = (m & 1) ? w4[m >> 1].z : w4[m >> 1].x;
                    const float sy = (m & 1) ? w4[m >> 1].w : w4[m >> 1].y;
                    accA[k] = __builtin_elementwise_fma((v2f){ sx, sx }, hv, accA[k]);
                    accB[k] = __builtin_elementwise_fma((v2f){ sy, sy }, hv, accB[k]);
                }
            }
            __builtin_amdgcn_sched_barrier(0);   // contain chunk live-ranges
        }

        go2[t0]     = make_float2(accA[0].x - accB[0].y, accA[0].y + accB[0].x);
        go2[t0 + 1] = make_float2(accA[1].x - accB[1].y, accA[1].y + accB[1].x);
    }

    const float2* S2 = (const float2*)S4;

    // ---- wave 0 extra: fused 64-pt DFT of zero-padded taps ----
    if (tid < MDFT) {
        const int kk = tid;
        v2f aA = (v2f)(0.f), aB = (v2f)(0.f);
        #pragma unroll
        for (int l = 0; l < TAPS; ++l) {
            const v2f hv = { hre[l], him[l] };
            float2 w = s_tw[(kk * l) & (MDFT - 1)];
            aA = __builtin_elementwise_fma((v2f){ w.x, w.x }, hv, aA);
            aB = __builtin_elementwise_fma((v2f){ w.y, w.y }, hv, aB);
        }
        ((float2*)out1)[(size_t)row * MDFT + kk] =
            make_float2(aA.x - aB.y, aA.y + aB.x);
    }
    // ---- wave 2 extra: leftover outputs t=0 and t=2049..2078 ----
    else if (tid >= 128 && tid <= 158) {
        const int t = (tid == 158) ? 0 : (2049 + (tid - 128));
        v2f aA = (v2f)(0.f), aB = (v2f)(0.f);
        #pragma unroll
        for (int l = 0; l < TAPS; ++l) {
            const v2f hv = { hre[l], him[l] };
            float2 s = S2[PAD + t - l];      // pads supply zeros both ends
            aA = __builtin_elementwise_fma((v2f){ s.x, s.x }, hv, aA);
            aB = __builtin_elementwise_fma((v2f){ s.y, s.y }, hv, aB);
        }
        go2[t] = make_float2(aA.x - aB.y, aA.y + aB.x);
    }
}

extern "C" void kernel_launch(void* const* d_in, const int* in_sizes, int n_in,
                              void* d_out, int out_size, void* d_ws, size_t ws_size,
                              hipStream_t stream)
{
    const float* input = (const float*)d_in[0];  // (N,P,2048,2) fp32
    const float* cof   = (const float*)d_in[1];  // (N,P,32,2)   fp32
    // d_in[2] is M (=64), compile-time here.

    const int NP = in_sizes[0] / (SMK * 2);      // 16384

    float* out0 = (float*)d_out;                           // (NP, 2079, 2)
    float* out1 = out0 + (size_t)NP * OUTLEN * 2;          // (NP, 64, 2)

    conv_kernel<<<NP, 256, 0, stream>>>(input, cof, out0, out1);
}